// Round 3
// 923.162 us; speedup vs baseline: 1.0622x; 1.0622x over previous
//
#include <hip/hip_runtime.h>
#include <hip/hip_bf16.h>
#include <cmath>

// Problem constants
#define L_SEQ  1024
#define BATCH  16
#define NOUT   512          // n
#define DIN    1024         // 2n = layer input dim = GEMM K
#define NBIG   3072         // 6n = GEMM N
#define NLAYERS 4
#define NTOK   (L_SEQ * BATCH)   // 16384 = GEMM M
#define NCHAIN 16384             // B * 2 * n independent scan chains
#define SEG    32                // segments per chain
#define SEGLEN (L_SEQ / SEG)     // 32 steps per segment

typedef __attribute__((ext_vector_type(8))) short bf16x8;
typedef __attribute__((ext_vector_type(4))) float f32x4;

__device__ __forceinline__ unsigned short f2bf(float f) {
    unsigned x = __float_as_uint(f);
    unsigned r = (x + 0x7fffu + ((x >> 16) & 1u)) >> 16;   // RNE
    return (unsigned short)r;
}
__device__ __forceinline__ float bf2f(unsigned short hv) {
    return __uint_as_float((unsigned)hv << 16);
}
__device__ __forceinline__ float sigmf(float v) {
    return 1.f / (1.f + __expf(-v));
}
__device__ __forceinline__ void async16(const void* g, const void* l) {
    __builtin_amdgcn_global_load_lds(
        (const __attribute__((address_space(1))) unsigned int*)g,
        (__attribute__((address_space(3))) unsigned int*)l, 16, 0, 0);
}

// ---------------- W convert + transpose: W(1024,3072) f32 -> Wt(3072,1024) bf16 ----------------
__global__ __launch_bounds__(256)
void transpose_w(const float* __restrict__ Ws, unsigned short* __restrict__ Wt) {
    __shared__ float tile[32][33];
    int l = blockIdx.z;
    const float* W = Ws + (size_t)l * DIN * NBIG;
    unsigned short* Wo = Wt + (size_t)l * NBIG * DIN;
    int n0 = blockIdx.x * 32, k0 = blockIdx.y * 32;
    int tx = threadIdx.x & 31, ty = threadIdx.x >> 5;
    #pragma unroll
    for (int i = 0; i < 4; i++)
        tile[ty + 8 * i][tx] = W[(size_t)(k0 + ty + 8 * i) * NBIG + n0 + tx];
    __syncthreads();
    #pragma unroll
    for (int i = 0; i < 4; i++)
        Wo[(size_t)(n0 + ty + 8 * i) * DIN + k0 + tx] = f2bf(tile[tx][ty + 8 * i]);
}

// ---------------- embedding gather: write x fp32 + xbf bf16 ----------------
__global__ void embed_kernel(const int* __restrict__ tok,
                             const float* __restrict__ emb,
                             float* __restrict__ x,
                             unsigned short* __restrict__ xbf) {
    int t = blockIdx.x;
    int row = tok[t];
    float4 v = ((const float4*)(emb + (size_t)row * DIN))[threadIdx.x];
    ((float4*)(x + (size_t)t * DIN))[threadIdx.x] = v;
    ushort4 h;
    h.x = f2bf(v.x); h.y = f2bf(v.y); h.z = f2bf(v.z); h.w = f2bf(v.w);
    ((ushort4*)(xbf + (size_t)t * DIN))[threadIdx.x] = h;
}

// ---------------- bf16 MFMA GEMM: u = x @ W ----------------
// 256x256 tile, BK=64, 8 waves (2M x 4N), per-wave 128x64 output (8x4 frags).
// 8-phase schedule; STAGED UNIT == READ STRIPE:
//   A-stripe mh = rows {q*128 + mh*64 + w*8}   (what LOAD_A(.,mh) reads)
//   B-stripe nh = rows {g*64  + nh*32 + u*8}   (what LOAD_B(.,nh) reads)
// Reads per K-tile: P1 {A0,B0} -> MMA(0,0); P2 {B1} -> MMA(0,1);
// P3 {A1} -> MMA(1,1); P4 {B0 re-read} -> MMA(1,0).
// Region read at phase p is stage-safe at p+1 (lgkmcnt(0)+barrier per phase).
// Stage slots: P1 B0(2t+1)->buf1 | P2 A0(2t+2) | P3 B1(2t+2) | P4 A1(2t+2)
//            | P5 B0(2t+2)->buf0 | P6 A0(2t+3) | P7 B1(2t+3) | P8 A1(2t+3).
// vmcnt(6) at P4/P8 only: 7 stages (14 loads) outstanding there; oldest 4
// stages == the full next-buffer K-tile. Never drains in steady state.
// LDS chunk-XOR swizzle: 16B chunk c of row r at slot c^(r&7); staged via
// source-side permutation (lane L: dest slot L&7, src chunk (L&7)^(L>>3)).
// Epilogue: planes (xt,f,r) -> bf16, layout [tok][dir*512 + feat].

#define STAGE_A(b, mh, kt, src)                                             \
    do {                                                                    \
        _Pragma("unroll")                                                   \
        for (int q = 0; q < 2; q++) {                                       \
            int rbase = q * 128 + (mh) * 64 + w * 8;                        \
            async16((src) + (size_t)(rbase + sr) * DIN + (kt) * 64 + sc * 8,\
                    &lds[b][0][rbase * 64]);                                \
        }                                                                   \
    } while (0)

#define STAGE_B(b, nh, kt, src)                                             \
    do {                                                                    \
        _Pragma("unroll")                                                   \
        for (int q = 0; q < 2; q++) {                                       \
            int gi = q * 8 + w;                                             \
            int rbase = (gi >> 2) * 64 + (nh) * 32 + (gi & 3) * 8;          \
            async16((src) + (size_t)(rbase + sr) * DIN + (kt) * 64 + sc * 8,\
                    &lds[b][1][rbase * 64]);                                \
        }                                                                   \
    } while (0)

#define LOAD_A(b, mh)                                                       \
    do {                                                                    \
        _Pragma("unroll")                                                   \
        for (int i = 0; i < 4; i++) {                                       \
            int ra = wm * 128 + (mh) * 64 + i * 16 + l16;                   \
            _Pragma("unroll")                                               \
            for (int kk = 0; kk < 2; kk++) {                                \
                int slot = (kk * 4 + quad) ^ (ra & 7);                      \
                af[i][kk] = *(const bf16x8*)&lds[b][0][ra * 64 + slot * 8]; \
            }                                                               \
        }                                                                   \
    } while (0)

#define LOAD_B(b, nh)                                                       \
    do {                                                                    \
        _Pragma("unroll")                                                   \
        for (int j = 0; j < 2; j++) {                                       \
            int rb = wn * 64 + (nh) * 32 + j * 16 + l16;                    \
            _Pragma("unroll")                                               \
            for (int kk = 0; kk < 2; kk++) {                                \
                int slot = (kk * 4 + quad) ^ (rb & 7);                      \
                bg[j][kk] = *(const bf16x8*)&lds[b][1][rb * 64 + slot * 8]; \
            }                                                               \
        }                                                                   \
    } while (0)

#define MMA(mh, nh)                                                         \
    do {                                                                    \
        __builtin_amdgcn_s_setprio(1);                                      \
        _Pragma("unroll")                                                   \
        for (int i = 0; i < 4; i++)                                         \
            _Pragma("unroll")                                               \
            for (int j = 0; j < 2; j++)                                     \
                _Pragma("unroll")                                           \
                for (int kk = 0; kk < 2; kk++)                              \
                    acc[(mh) * 4 + i][(nh) * 2 + j] =                       \
                        __builtin_amdgcn_mfma_f32_16x16x32_bf16(            \
                            af[i][kk], bg[j][kk],                           \
                            acc[(mh) * 4 + i][(nh) * 2 + j], 0, 0, 0);      \
        __builtin_amdgcn_s_setprio(0);                                      \
    } while (0)

#define BAR()   __builtin_amdgcn_s_barrier()
#define LGKM0() do { asm volatile("s_waitcnt lgkmcnt(0)" ::: "memory");     \
                     __builtin_amdgcn_sched_barrier(0); } while (0)
#define LGKM8() asm volatile("s_waitcnt lgkmcnt(8)" ::: "memory")
#define VM6()   asm volatile("s_waitcnt vmcnt(6)" ::: "memory")
#define VM0()   asm volatile("s_waitcnt vmcnt(0)" ::: "memory")

__global__ __launch_bounds__(512)
void gemm_bf16(const unsigned short* __restrict__ Abf,
               const unsigned short* __restrict__ Bt,
               unsigned short* __restrict__ u_xt,
               unsigned short* __restrict__ u_f,
               unsigned short* __restrict__ u_r) {
    __shared__ __align__(16) unsigned short lds[2][2][256 * 64];  // [buf][A/B]

    const int tid  = threadIdx.x;
    const int lane = tid & 63;
    const int w    = tid >> 6;          // wave 0..7
    const int wm   = w >> 2, wn = w & 3;
    const int quad = lane >> 4, l16 = lane & 15;

    // XCD-aware bijective swizzle: grid 12x64 = 768 blocks, 768 % 8 == 0.
    const int flat = blockIdx.y * (NBIG / 256) + blockIdx.x;
    const int swz  = (flat & 7) * (NTOK / 256 * NBIG / 256 / 8) + (flat >> 3);
    const int M0 = (swz / (NBIG / 256)) * 256;
    const int N0 = (swz % (NBIG / 256)) * 256;

    const unsigned short* Asrc = Abf + (size_t)M0 * DIN;
    const unsigned short* Bsrc = Bt  + (size_t)N0 * DIN;

    f32x4 acc[8][4];
    #pragma unroll
    for (int i = 0; i < 8; i++)
        #pragma unroll
        for (int j = 0; j < 4; j++)
            acc[i][j] = (f32x4){0.f, 0.f, 0.f, 0.f};

    // staging lane coords (8-row groups, 8 chunks/row)
    const int sr = lane >> 3;           // row within group 0..7
    const int sc = (lane & 7) ^ sr;     // source k-chunk (swizzle inverse)

    bf16x8 af[4][2], bg[2][2];

    // Prologue: tile0 (all 4 stripes) -> buf0; tile1 {A0,B1,A1} -> buf1.
    // vmcnt(6) leaves exactly tile1's 3 stripes in flight; tile0 landed.
    STAGE_A(0, 0, 0, Asrc); STAGE_B(0, 0, 0, Bsrc);
    STAGE_B(0, 1, 0, Bsrc); STAGE_A(0, 1, 0, Asrc);
    STAGE_A(1, 0, 1, Asrc); STAGE_B(1, 1, 1, Bsrc); STAGE_A(1, 1, 1, Asrc);
    VM6();
    BAR();

    const int NITER = DIN / 128;        // 8 iterations x 2 K-tiles
    for (int t = 0; t < NITER; t++) {
        const int k1 = 2 * t + 1;
        const bool more = (t < NITER - 1);

        // ---- K-tile 2t from buf0 ----
        // P1: reads A0,B0(buf0); stages B0(2t+1)->buf1 (old read prev P8)
        LOAD_A(0, 0); LOAD_B(0, 0);
        STAGE_B(1, 0, k1, Bsrc);
        LGKM8(); BAR(); LGKM0(); MMA(0, 0); BAR();
        // P2: reads B1(buf0); stages A0(2t+2)->buf0 (A0 read at P1)
        LOAD_B(0, 1);
        if (more) STAGE_A(0, 0, k1 + 1, Asrc);
        BAR(); LGKM0(); MMA(0, 1); BAR();
        // P3: reads A1(buf0); stages B1(2t+2)->buf0 (B1 read at P2)
        LOAD_A(0, 1);
        if (more) STAGE_B(0, 1, k1 + 1, Bsrc);
        BAR(); LGKM0(); MMA(1, 1); BAR();
        // P4: re-reads B0(buf0); stages A1(2t+2)->buf0 (A1 read at P3);
        //     vmcnt(6): oldest 4 of 7 outstanding stages == full tile 2t+1
        LOAD_B(0, 0);
        if (more) { STAGE_A(0, 1, k1 + 1, Asrc); VM6(); }
        else      { VM0(); }
        BAR(); LGKM0(); MMA(1, 0); BAR();

        // ---- K-tile 2t+1 from buf1 ----
        // P5: reads A0,B0(buf1); stages B0(2t+2)->buf0 (B0 read P1+P4)
        LOAD_A(1, 0); LOAD_B(1, 0);
        if (more) STAGE_B(0, 0, k1 + 1, Bsrc);
        LGKM8(); BAR(); LGKM0(); MMA(0, 0); BAR();
        // P6: reads B1(buf1); stages A0(2t+3)->buf1 (A0 read at P5)
        LOAD_B(1, 1);
        if (more) STAGE_A(1, 0, k1 + 2, Asrc);
        BAR(); LGKM0(); MMA(0, 1); BAR();
        // P7: reads A1(buf1); stages B1(2t+3)->buf1 (B1 read at P6)
        LOAD_A(1, 1);
        if (more) STAGE_B(1, 1, k1 + 2, Bsrc);
        BAR(); LGKM0(); MMA(1, 1); BAR();
        // P8: re-reads B0(buf1); stages A1(2t+3)->buf1 (A1 read at P7);
        //     vmcnt(6): oldest 4 outstanding == full tile 2t+2
        LOAD_B(1, 0);
        if (more) { STAGE_A(1, 1, k1 + 2, Asrc); VM6(); }
        BAR(); LGKM0(); MMA(1, 0); BAR();
    }

    // Epilogue: split planes, bf16 store.
    #pragma unroll
    for (int i = 0; i < 8; i++) {
        int gm = M0 + wm * 128 + i * 16 + quad * 4;
        #pragma unroll
        for (int j = 0; j < 4; j++) {
            int gn = N0 + wn * 64 + j * 16 + l16;
            int dir  = gn >= 3 * NOUT;
            int jj   = gn - dir * 3 * NOUT;
            int plane = jj >> 9;          // 0:xt 1:f 2:r (uniform per 16-tile)
            int feat  = jj & 511;
            unsigned short* p = (plane == 0 ? u_xt : plane == 1 ? u_f : u_r)
                                + (size_t)gm * DIN + dir * NOUT + feat;
            #pragma unroll
            for (int r = 0; r < 4; r++) p[(size_t)r * DIN] = f2bf(acc[i][j][r]);
        }
    }
}

// ---------------- chunked SRU scan ----------------
// chain = b*1024 + d*512 + i  (0..16383); element index at time t: t*16384 + chain.
// Segment s: steps j=0..31 at t = t0 + sgn*j; d=0: t0=s*32,sgn=+1; d=1: t0=1023-s*32,sgn=-1.

// Phase A: per (chain, seg) compute A=prod f, B=scan-from-0 result.
__global__ __launch_bounds__(256)
void scan_phaseA(const unsigned short* __restrict__ u_xt, const unsigned short* __restrict__ u_f,
                 const float* __restrict__ bias,
                 float* __restrict__ Aseg, float* __restrict__ Bseg) {
    int g = blockIdx.x * 256 + threadIdx.x;     // s*16384 + chain
    int chain = g & (NCHAIN - 1);
    int s = g >> 14;
    int rest = chain & 1023;                    // d*512 + i
    float bf = bias[rest];

    int d = rest >> 9;
    int t0 = d ? (L_SEQ - 1 - s * SEGLEN) : (s * SEGLEN);
    int sgn = d ? -1 : 1;
    long long idx = (long long)t0 * NCHAIN + chain;
    long long step = (long long)sgn * NCHAIN;

    float c = 0.f, A = 1.f;
    #pragma unroll 8
    for (int j = 0; j < SEGLEN; j++) {
        float xt = bf2f(u_xt[idx]);
        float f = sigmf(bf2f(u_f[idx]) + bf);
        c = f * c + (1.f - f) * xt;
        A *= f;
        idx += step;
    }
    Aseg[g] = A;
    Bseg[g] = c;
}

// Phase B: compose segment carries per chain; write cstart per segment and
// the final c (== hidden state, layout (B,2n) flat == chain).
__global__ __launch_bounds__(256)
void scan_phaseB(const float* __restrict__ Aseg, const float* __restrict__ Bseg,
                 float* __restrict__ cstart, float* __restrict__ c_out) {
    int chain = blockIdx.x * 256 + threadIdx.x;
    float c = 0.f;
    #pragma unroll
    for (int s = 0; s < SEG; s++) {
        int g = s * NCHAIN + chain;
        cstart[g] = c;
        c = Aseg[g] * c + Bseg[g];
    }
    c_out[chain] = c;
}

// Phase C: re-scan each segment from true cstart, emit h (in-place on x) + bf16 copy.
__global__ __launch_bounds__(256)
void scan_phaseC(const unsigned short* __restrict__ u_xt, const unsigned short* __restrict__ u_f,
                 const unsigned short* __restrict__ u_r,
                 float* __restrict__ x, unsigned short* __restrict__ xbf,
                 const float* __restrict__ bias, const float* __restrict__ cstart,
                 int write_bf) {
    int g = blockIdx.x * 256 + threadIdx.x;
    int chain = g & (NCHAIN - 1);
    int s = g >> 14;
    int rest = chain & 1023;
    float bf = bias[rest];
    float br = bias[1024 + rest];

    int d = rest >> 9;
    int t0 = d ? (L_SEQ - 1 - s * SEGLEN) : (s * SEGLEN);
    int sgn = d ? -1 : 1;
    long long idx = (long long)t0 * NCHAIN + chain;
    long long step = (long long)sgn * NCHAIN;

    float c = cstart[g];
    #pragma unroll 4
    for (int j = 0; j < SEGLEN; j++) {
        float xt = bf2f(u_xt[idx]);
        float f = sigmf(bf2f(u_f[idx]) + bf);
        float r = sigmf(bf2f(u_r[idx]) + br);
        float xp = x[idx];
        c = f * c + (1.f - f) * xt;
        float th = 1.f - 2.f / (__expf(2.f * c) + 1.f);
        float h = r * th + (1.f - r) * xp;
        x[idx] = h;
        if (write_bf) xbf[idx] = f2bf(h);
        idx += step;
    }
}

// ---------------- launch ----------------
// d_out: [ x (L*B*1024) | hidden (4*B*1024) ] f32.
// Workspace (158 MB): u_xt 32 | u_f 32 | u_r 32 | xbf 32 | Wt 24 | Aseg 2 | Bseg 2 | cstart 2.
extern "C" void kernel_launch(void* const* d_in, const int* in_sizes, int n_in,
                              void* d_out, int out_size, void* d_ws, size_t ws_size,
                              hipStream_t stream) {
    const int*   tok = (const int*)d_in[0];
    const float* emb = (const float*)d_in[2];
    const float* Ws  = (const float*)d_in[3];
    const float* bs  = (const float*)d_in[4];

    float* out    = (float*)d_out;
    float* x      = out;
    float* hidden = out + (size_t)NTOK * DIN;

    char* ws = (char*)d_ws;
    unsigned short* u_xt   = (unsigned short*)ws;                       // 32 MB
    unsigned short* u_f    = (unsigned short*)(ws + (32u  << 20));      // 32 MB
    unsigned short* u_r    = (unsigned short*)(ws + (64u  << 20));      // 32 MB
    unsigned short* xbf    = (unsigned short*)(ws + (96u  << 20));      // 32 MB
    unsigned short* Wt     = (unsigned short*)(ws + (128u << 20));      // 24 MB
    float*          Aseg   = (float*)(ws + (152u << 20));               // 2 MB
    float*          Bseg   = (float*)(ws + (154u << 20));               // 2 MB
    float*          cstart = (float*)(ws + (156u << 20));               // 2 MB

    transpose_w<<<dim3(NBIG / 32, DIN / 32, NLAYERS), 256, 0, stream>>>(Ws, Wt);
    embed_kernel<<<NTOK, 256, 0, stream>>>(tok, emb, x, xbf);

    const int scan_blocks = NCHAIN * SEG / 256;   // 2048

    for (int l = 0; l < NLAYERS; l++) {
        const unsigned short* Wl = Wt + (size_t)l * NBIG * DIN;
        const float* b = bs + (size_t)l * 4 * NOUT;
        gemm_bf16<<<dim3(NBIG / 256, NTOK / 256), 512, 0, stream>>>(xbf, Wl, u_xt, u_f, u_r);
        scan_phaseA<<<scan_blocks, 256, 0, stream>>>(u_xt, u_f, b, Aseg, Bseg);
        scan_phaseB<<<NCHAIN / 256, 256, 0, stream>>>(Aseg, Bseg, cstart,
                                                      hidden + (size_t)l * BATCH * DIN);
        scan_phaseC<<<scan_blocks, 256, 0, stream>>>(u_xt, u_f, u_r, x, xbf, b, cstart,
                                                     l < NLAYERS - 1);
    }
}